// Round 6
// baseline (382.759 us; speedup 1.0000x reference)
//
#include <hip/hip_runtime.h>
#include <stdint.h>

#define S_LEN 2048
#define HDIM  2048
#define N_HEADS 16
#define HEAD_D 128
#define N_KV 4

typedef unsigned short u16;
typedef __attribute__((ext_vector_type(8))) short bf16x8;
typedef __attribute__((ext_vector_type(4))) short bf16x4;
typedef __attribute__((ext_vector_type(4))) float f32x4;

// K=16 bf16 MFMA (v_mfma_f32_16x16x16_bf16, 2 A-regs = bf16x4 operands).
// NOTE: call directly — __has_builtin() is false in the HIP host pass even
// though the builtin resolves in both passes.
#define MFMA_PV(a, b, c) __builtin_amdgcn_mfma_f32_16x16x16bf16_1k(a, b, c, 0, 0, 0)

__device__ __forceinline__ u16 f2bf(float f) {
  unsigned u = __float_as_uint(f);
  u += 0x7FFFu + ((u >> 16) & 1u);
  return (u16)(u >> 16);
}

__device__ __forceinline__ void gll16(void* lds, const void* gp) {
  __builtin_amdgcn_global_load_lds(
      (const __attribute__((address_space(1))) void*)gp,
      (__attribute__((address_space(3))) void*)lds, 16, 0, 0);
}

// ---------------- fp32 -> bf16 convert (vectorized) ----------------
__global__ __launch_bounds__(256) void k_convert(const float* __restrict__ src,
                                                 u16* __restrict__ dst, int n4) {
  int i = blockIdx.x * 256 + threadIdx.x;
  if (i < n4) {
    float4 v = ((const float4*)src)[i];
    ushort4 o;
    o.x = f2bf(v.x); o.y = f2bf(v.y); o.z = f2bf(v.z); o.w = f2bf(v.w);
    ((ushort4*)dst)[i] = o;
  }
}

// ---------------- W [K][N] fp32 -> Wt [N][K] bf16 ----------------
__global__ __launch_bounds__(256) void k_transpose_w(const float* __restrict__ W,
                                                     u16* __restrict__ Wt,
                                                     int K, int N) {
  __shared__ float tile[64][65];
  int k0 = blockIdx.x * 64, n0 = blockIdx.y * 64;
  int tr = threadIdx.x >> 6, tc = threadIdx.x & 63;
#pragma unroll
  for (int i = 0; i < 16; ++i) {
    int r = tr + i * 4;
    tile[r][tc] = W[(size_t)(k0 + r) * N + n0 + tc];
  }
  __syncthreads();
#pragma unroll
  for (int i = 0; i < 16; ++i) {
    int r = tr + i * 4;  // n offset
    Wt[(size_t)(n0 + r) * K + k0 + tc] = f2bf(tile[tc][r]);
  }
}

// ---------------- 128x128 bf16 MFMA GEMM tile (A[M][K], Bt[N][K]) ----------------
__device__ __forceinline__ void gemm_tile_128(
    const u16* __restrict__ A, const u16* __restrict__ Bt,
    const float* __restrict__ bias, float* __restrict__ C,
    int m0, int n0, int K, int ldc) {
  __shared__ __align__(16) u16 sA[128 * 32];
  __shared__ __align__(16) u16 sB[128 * 32];
  const int tid = threadIdx.x;
  const int lane = tid & 63;
  const int wave = tid >> 6;
  const int quad = lane >> 4;
  const int l15 = lane & 15;
  const int wm = (wave >> 1) << 6;
  const int wn = (wave & 1) << 6;

  f32x4 acc[4][4];
#pragma unroll
  for (int i = 0; i < 4; ++i)
#pragma unroll
    for (int j = 0; j < 4; ++j)
      acc[i][j] = (f32x4){0.f, 0.f, 0.f, 0.f};

  for (int kk = 0; kk < K; kk += 32) {
    __syncthreads();
#pragma unroll
    for (int it = 0; it < 2; ++it) {
      int c = tid + (it << 8);     // 512 chunks of 16B per tile
      int row = c >> 2;
      int ko = (c & 3) << 3;
      gll16((char*)sA + c * 16, A + (size_t)(m0 + row) * K + kk + ko);
      gll16((char*)sB + c * 16, Bt + (size_t)(n0 + row) * K + kk + ko);
    }
    __syncthreads();
    bf16x8 af[4], bfr[4];
#pragma unroll
    for (int i = 0; i < 4; ++i)
      af[i] = *(const bf16x8*)&sA[(wm + (i << 4) + l15) * 32 + quad * 8];
#pragma unroll
    for (int j = 0; j < 4; ++j)
      bfr[j] = *(const bf16x8*)&sB[(wn + (j << 4) + l15) * 32 + quad * 8];
#pragma unroll
    for (int i = 0; i < 4; ++i)
#pragma unroll
      for (int j = 0; j < 4; ++j)
        acc[i][j] = __builtin_amdgcn_mfma_f32_16x16x32_bf16(af[i], bfr[j], acc[i][j], 0, 0, 0);
  }

#pragma unroll
  for (int i = 0; i < 4; ++i) {
    int row = m0 + wm + (i << 4) + quad * 4;
#pragma unroll
    for (int j = 0; j < 4; ++j) {
      int col = n0 + wn + (j << 4) + l15;
      float bv = bias[col];
      float* cp = C + (size_t)row * ldc + col;
#pragma unroll
      for (int r = 0; r < 4; ++r)
        cp[(size_t)r * ldc] = acc[i][j][r] + bv;
    }
  }
}

__global__ __launch_bounds__(256) void k_gemm_qkv(
    const u16* __restrict__ X, const u16* __restrict__ Wqt,
    const u16* __restrict__ Wkt, const u16* __restrict__ Wvt,
    const float* __restrict__ bq, const float* __restrict__ bk,
    const float* __restrict__ bv, float* __restrict__ Qf,
    float* __restrict__ Kf, float* __restrict__ Vf) {
  int m0 = blockIdx.x << 7;
  int by = blockIdx.y;
  const u16* Bt; const float* bias; float* C; int n0, ldc;
  if (by < 16)      { Bt = Wqt; bias = bq; C = Qf; n0 = by << 7;        ldc = 2048; }
  else if (by < 20) { Bt = Wkt; bias = bk; C = Kf; n0 = (by - 16) << 7; ldc = 512;  }
  else              { Bt = Wvt; bias = bv; C = Vf; n0 = (by - 20) << 7; ldc = 512;  }
  gemm_tile_128(X, Bt, bias, C, m0, n0, 2048, ldc);
}

__global__ __launch_bounds__(256) void k_gemm_o(
    const u16* __restrict__ A, const u16* __restrict__ Wot,
    const float* __restrict__ bo, float* __restrict__ C) {
  gemm_tile_128(A, Wot, bo, C, blockIdx.x << 7, blockIdx.y << 7, 2048, 2048);
}

// ---------------- RoPE: Qf/Kf fp32 -> Qbf [b,h,s,d], Kbf [b,kvh,s,d] bf16 + past_key fp32 ----------------
__global__ __launch_bounds__(256) void k_rope(
    const float* __restrict__ Qf, const float* __restrict__ Kf,
    u16* __restrict__ Qbf, u16* __restrict__ Kbf, float* __restrict__ outK) {
  const int bx = blockIdx.x;         // b*S + s
  const int b = bx >> 11;
  const int s = bx & 2047;
  const int tid = threadIdx.x;
  // 1/sqrt(128) * log2(e) folded into Q so softmax can use exp2
  const float qscale = 0.08838834764831845f * 1.4426950408889634f;
  const float c1 = -13.287712379549449f / 64.f; // -log2(10000)/64

#pragma unroll
  for (int it = 0; it < 4; ++it) {
    int p = tid + (it << 8);
    int hh = p >> 6;
    int ii = p & 63;
    float ang = (float)s * exp2f((float)ii * c1);
    float cs, sn;
    sincosf(ang, &sn, &cs);
    const float* src = Qf + (size_t)bx * 2048 + hh * 128 + ii;
    float x1 = src[0], x2 = src[64];
    float o1 = (x1 * cs - x2 * sn) * qscale;
    float o2 = (x1 * sn + x2 * cs) * qscale;
    u16* dst = Qbf + ((size_t)(b * N_HEADS + hh) * S_LEN + s) * HEAD_D + ii;
    dst[0] = f2bf(o1);
    dst[64] = f2bf(o2);
  }
  {
    int hh = tid >> 6;   // kv head (4 heads * 64 pairs = 256 threads)
    int ii = tid & 63;
    float ang = (float)s * exp2f((float)ii * c1);
    float cs, sn;
    sincosf(ang, &sn, &cs);
    const float* src = Kf + (size_t)bx * 512 + hh * 128 + ii;
    float x1 = src[0], x2 = src[64];
    float o1 = x1 * cs - x2 * sn;
    float o2 = x1 * sn + x2 * cs;
    size_t idx = ((size_t)(b * N_KV + hh) * S_LEN + s) * HEAD_D + ii;
    Kbf[idx] = f2bf(o1);
    Kbf[idx + 64] = f2bf(o2);
    outK[idx] = o1;
    outK[idx + 64] = o2;
  }
}

// ---------------- V: Vf fp32 [b,s,kvh*d] -> Vt bf16 [b,kvh,d,s] + past_value fp32 ----------------
__global__ __launch_bounds__(256) void k_vtrans(const float* __restrict__ Vf,
                                                u16* __restrict__ Vt,
                                                float* __restrict__ outV) {
  __shared__ float tile[64][65];
  int s0 = blockIdx.x * 64, d0 = blockIdx.y * 64;
  int z = blockIdx.z;                 // b*N_KV + kvh
  int b = z >> 2, kvh = z & 3;
  int tr = threadIdx.x >> 6, tc = threadIdx.x & 63;
#pragma unroll
  for (int i = 0; i < 16; ++i) {
    int r = tr + i * 4;   // s offset
    float v = Vf[(size_t)(b * S_LEN + s0 + r) * 512 + kvh * 128 + d0 + tc];
    tile[r][tc] = v;
    outV[((size_t)z * S_LEN + s0 + r) * HEAD_D + d0 + tc] = v;
  }
  __syncthreads();
#pragma unroll
  for (int i = 0; i < 16; ++i) {
    int r = tr + i * 4;   // d offset
    Vt[((size_t)z * HEAD_D + d0 + r) * S_LEN + s0 + tc] = f2bf(tile[tc][r]);
  }
}

// ---------------- flash attention, S^T formulation, 2-wave blocks ----------------
// 64-row Q tile per 128-thread block (2 waves x 32 q-rows). Grid 32x32 = 1024
// blocks, ALL co-resident (4 blocks/CU: LDS 4x35KB=140KB, 8 waves/CU) ->
// independent blocks overlap VALU/LDS/MFMA pipes (r5 was 1 wave/SIMD
// serialized). Per-CU work balanced exactly: CU hosts by = {b, b+8, b+16,
// b+24} -> qt = {b, 15-b, 16+b, 31-b}, ntiles sum = 66 for every CU.
__global__ __launch_bounds__(128, 2) void k_attn(
    const u16* __restrict__ Qbf, const u16* __restrict__ Kbf,
    const u16* __restrict__ Vt, u16* __restrict__ attn) {
  __shared__ __align__(16) u16 smem[17920];   // 35840 B
  u16* sK = smem;            // 64 x 136  (8704)
  u16* sV = smem + 8704;     // 128 x 72  (9216)

  const int tid = threadIdx.x;
  const int lane = tid & 63;
  const int wave = tid >> 6;          // 0..1
  const int quad = lane >> 4;
  const int l15 = lane & 15;

  // per-CU balanced qt map (see header comment)
  const int by = blockIdx.y;
  const int u = by >> 3, bb = by & 7;
  const int qt = (u == 0) ? bb : (u == 1) ? (15 - bb) : (u == 2) ? (16 + bb) : (31 - bb);
  const int bh = blockIdx.x;
  const int b = bh >> 4;
  const int h = bh & 15;
  const int kvh = h >> 2;
  const int q0 = qt << 6;
  const int qw = q0 + wave * 32;      // this wave's first q row

  const u16* Qb = Qbf + ((size_t)(b * N_HEADS + h) * S_LEN + qw) * HEAD_D;
  const u16* Kb = Kbf + (size_t)(b * N_KV + kvh) * S_LEN * HEAD_D;
  const u16* Vb = Vt + (size_t)(b * N_KV + kvh) * HEAD_D * S_LEN;

  // Q fragments (B-operand: lane holds Q[q=l15][d=quad*8+j]) for 2 row-groups
  bf16x8 aq[2][4];
#pragma unroll
  for (int i = 0; i < 2; ++i)
#pragma unroll
    for (int kc = 0; kc < 4; ++kc)
      aq[i][kc] = *(const bf16x8*)(Qb + (size_t)(i * 16 + l15) * HEAD_D + kc * 32 + quad * 8);

  float mst[2] = {-1e30f, -1e30f}, lst[2] = {0.f, 0.f};
  f32x4 oacc[2][8];
#pragma unroll
  for (int i = 0; i < 2; ++i)
#pragma unroll
    for (int n = 0; n < 8; ++n) oacc[i][n] = (f32x4){0.f, 0.f, 0.f, 0.f};

  const int ntiles = qt + 1;
  for (int t = 0; t < ntiles; ++t) {
    const int kt0 = t << 6;
    __syncthreads();
    // stage K (64x17 chunks = 1088) + V (128x9 = 1152) with 128 threads
#pragma unroll
    for (int it = 0; it < 18; ++it) {
      int c = tid + (it << 7);
      if (c < 1088) {
        int row = c / 17;
        int k16 = c - row * 17;
        gll16((char*)sK + c * 16, Kb + (size_t)(kt0 + row) * HEAD_D + k16 * 8);
      } else if (c < 2240) {
        int vv = c - 1088;
        int d = vv / 9;
        int s16 = vv - d * 9;
        gll16((char*)sV + vv * 16, Vb + (size_t)d * S_LEN + kt0 + s16 * 8);
      }
    }
    __syncthreads();

    // S^T = K * Q^T : lane holds S[q=l15][s=quad*4+r] per 16x16 j-tile
    f32x4 st[2][4];
#pragma unroll
    for (int i = 0; i < 2; ++i)
#pragma unroll
      for (int j = 0; j < 4; ++j) st[i][j] = (f32x4){0.f, 0.f, 0.f, 0.f};
#pragma unroll
    for (int kc = 0; kc < 4; ++kc) {
#pragma unroll
      for (int j = 0; j < 4; ++j) {
        bf16x8 kf = *(const bf16x8*)&sK[(j * 16 + l15) * 136 + kc * 32 + quad * 8];
#pragma unroll
        for (int i = 0; i < 2; ++i)
          st[i][j] = __builtin_amdgcn_mfma_f32_16x16x32_bf16(kf, aq[i][kc], st[i][j], 0, 0, 0);
      }
    }

    if (t == qt) {                    // diagonal tile: causal mask
#pragma unroll
      for (int i = 0; i < 2; ++i) {
        int q = qw + i * 16 + l15;
#pragma unroll
        for (int j = 0; j < 4; ++j) {
          int s = kt0 + j * 16 + quad * 4;
#pragma unroll
          for (int r = 0; r < 4; ++r)
            if (s + r > q) st[i][j][r] = -1e9f;
        }
      }
    }

    // online softmax; row stats live per-lane (q=l15), replicated across quads
    bf16x4 pf[2][4];
    float al[2];
#pragma unroll
    for (int i = 0; i < 2; ++i) {
      float m = -1e30f;
#pragma unroll
      for (int j = 0; j < 4; ++j)
#pragma unroll
        for (int r = 0; r < 4; ++r) m = fmaxf(m, st[i][j][r]);
      m = fmaxf(m, __shfl_xor(m, 16, 64));
      m = fmaxf(m, __shfl_xor(m, 32, 64));
      float mn = fmaxf(mst[i], m);
      al[i] = exp2f(mst[i] - mn);
      mst[i] = mn;
      float rs = 0.f;
#pragma unroll
      for (int j = 0; j < 4; ++j) {
        float p0 = exp2f(st[i][j][0] - mn);
        float p1 = exp2f(st[i][j][1] - mn);
        float p2 = exp2f(st[i][j][2] - mn);
        float p3 = exp2f(st[i][j][3] - mn);
        rs += (p0 + p1) + (p2 + p3);
        // pack 4 fp32 -> 4 bf16 via v_perm (half-up rounding): 6 VALU ops
        union { unsigned u[2]; bf16x4 v; } pk;
        pk.u[0] = __builtin_amdgcn_perm(__float_as_uint(p1) + 0x8000u,
                                        __float_as_uint(p0) + 0x8000u, 0x07060302u);
        pk.u[1] = __builtin_amdgcn_perm(__float_as_uint(p3) + 0x8000u,
                                        __float_as_uint(p2) + 0x8000u, 0x07060302u);
        pf[i][j] = pk.v;
      }
      rs += __shfl_xor(rs, 16, 64);
      rs += __shfl_xor(rs, 32, 64);
      lst[i] = lst[i] * al[i] + rs;
      // rescale O: rows of oacc are q=quad*4+r, fetch al for that row
#pragma unroll
      for (int r = 0; r < 4; ++r) {
        float a = __shfl(al[i], quad * 4 + r, 16);
#pragma unroll
        for (int n = 0; n < 8; ++n) oacc[i][n][r] *= a;
      }
    }

    // O += P*V via K=16 MFMA; P is already in A-layout in registers
#pragma unroll
    for (int j = 0; j < 4; ++j) {
#pragma unroll
      for (int n = 0; n < 8; ++n) {
        bf16x4 vf = *(const bf16x4*)&sV[(n * 16 + l15) * 72 + j * 16 + quad * 4];
#pragma unroll
        for (int i = 0; i < 2; ++i)
          oacc[i][n] = MFMA_PV(pf[i][j], vf, oacc[i][n]);
      }
    }
  }

  // normalize + write [b, s, h, d] bf16 for the O-projection
#pragma unroll
  for (int i = 0; i < 2; ++i)
#pragma unroll
    for (int r = 0; r < 4; ++r) {
      float inv = 1.0f / __shfl(lst[i], quad * 4 + r, 16);
      int row = qw + i * 16 + quad * 4 + r;
      u16* op = attn + ((size_t)b * S_LEN + row) * HDIM + h * HEAD_D;
#pragma unroll
      for (int n = 0; n < 8; ++n)
        op[n * 16 + l15] = f2bf(oacc[i][n][r] * inv);
    }
}

// ---------------- launch ----------------
extern "C" void kernel_launch(void* const* d_in, const int* in_sizes, int n_in,
                              void* d_out, int out_size, void* d_ws, size_t ws_size,
                              hipStream_t stream) {
  (void)in_sizes; (void)n_in; (void)out_size; (void)ws_size;
  const float* hs = (const float*)d_in[0];
  // d_in[1] = mask (causality is computed analytically)
  const float* Wq = (const float*)d_in[2];
  const float* bq = (const float*)d_in[3];
  const float* Wk = (const float*)d_in[4];
  const float* bk = (const float*)d_in[5];
  const float* Wv = (const float*)d_in[6];
  const float* bv = (const float*)d_in[7];
  const float* Wo = (const float*)d_in[8];
  const float* bo = (const float*)d_in[9];
  float* out = (float*)d_out;

  char* ws = (char*)d_ws;
  u16* Xbf   = (u16*)(ws + 0);          // 16.8 MB
  u16* Wqt   = (u16*)(ws + 16777216);   // 8.4 MB
  u16* Wkt   = (u16*)(ws + 25165824);   // 2.1 MB
  u16* Wvt   = (u16*)(ws + 27262976);   // 2.1 MB
  u16* Wot   = (u16*)(ws + 29360128);   // 8.4 MB
  float* Qf  = (float*)(ws + 37748736); // 33.6 MB
  float* Kf  = (float*)(ws + 71303168); // 8.4 MB
  float* Vf  = (float*)(ws + 79691776); // 8.4 MB
  u16* Qbf   = (u16*)(ws + 88080384);   // 16.8 MB
  u16* Kbf   = (u16*)(ws + 104857600);  // 4.2 MB
  u16* Vtb   = (u16*)(ws + 109051904);  // 4.2 MB (+16B pad slack follows)
  u16* attnb = (u16*)(ws + 37748736);   // aliases Qf (dead after k_rope)

  k_convert<<<8192, 256, 0, stream>>>(hs, Xbf, 2097152);
  k_transpose_w<<<dim3(32, 32), 256, 0, stream>>>(Wq, Wqt, 2048, 2048);
  k_transpose_w<<<dim3(32, 8), 256, 0, stream>>>(Wk, Wkt, 2048, 512);
  k_transpose_w<<<dim3(32, 8), 256, 0, stream>>>(Wv, Wvt, 2048, 512);
  k_transpose_w<<<dim3(32, 32), 256, 0, stream>>>(Wo, Wot, 2048, 2048);
  k_gemm_qkv<<<dim3(32, 24), 256, 0, stream>>>(Xbf, Wqt, Wkt, Wvt, bq, bk, bv, Qf, Kf, Vf);
  k_rope<<<4096, 256, 0, stream>>>(Qf, Kf, Qbf, Kbf, out + 8388608);
  k_vtrans<<<dim3(32, 2, 8), 256, 0, stream>>>(Vf, Vtb, out + 10485760);
  k_attn<<<dim3(32, 32), 128, 0, stream>>>(Qbf, Kbf, Vtb, attnb);
  k_gemm_o<<<dim3(32, 16), 256, 0, stream>>>(attnb, Wot, bo, out);
}

// Round 7
// 367.800 us; speedup vs baseline: 1.0407x; 1.0407x over previous
//
#include <hip/hip_runtime.h>
#include <stdint.h>

#define S_LEN 2048
#define HDIM  2048
#define N_HEADS 16
#define HEAD_D 128
#define N_KV 4

typedef unsigned short u16;
typedef __attribute__((ext_vector_type(8))) short bf16x8;
typedef __attribute__((ext_vector_type(4))) short bf16x4;
typedef __attribute__((ext_vector_type(4))) float f32x4;

// K=16 bf16 MFMA (v_mfma_f32_16x16x16_bf16, 2 A-regs = bf16x4 operands).
// NOTE: call directly — __has_builtin() is false in the HIP host pass even
// though the builtin resolves in both passes.
#define MFMA_PV(a, b, c) __builtin_amdgcn_mfma_f32_16x16x16bf16_1k(a, b, c, 0, 0, 0)

__device__ __forceinline__ u16 f2bf(float f) {
  unsigned u = __float_as_uint(f);
  u += 0x7FFFu + ((u >> 16) & 1u);
  return (u16)(u >> 16);
}

__device__ __forceinline__ float bf2f(u16 v) {
  return __uint_as_float(((unsigned)v) << 16);
}

__device__ __forceinline__ void gll16(void* lds, const void* gp) {
  __builtin_amdgcn_global_load_lds(
      (const __attribute__((address_space(1))) void*)gp,
      (__attribute__((address_space(3))) void*)lds, 16, 0, 0);
}

// ---------------- fp32 -> bf16 convert (vectorized) ----------------
__global__ __launch_bounds__(256) void k_convert(const float* __restrict__ src,
                                                 u16* __restrict__ dst, int n4) {
  int i = blockIdx.x * 256 + threadIdx.x;
  if (i < n4) {
    float4 v = ((const float4*)src)[i];
    ushort4 o;
    o.x = f2bf(v.x); o.y = f2bf(v.y); o.z = f2bf(v.z); o.w = f2bf(v.w);
    ((ushort4*)dst)[i] = o;
  }
}

// ---------------- W [K][N] fp32 -> Wt [N][K] bf16 ----------------
__global__ __launch_bounds__(256) void k_transpose_w(const float* __restrict__ W,
                                                     u16* __restrict__ Wt,
                                                     int K, int N) {
  __shared__ float tile[64][65];
  int k0 = blockIdx.x * 64, n0 = blockIdx.y * 64;
  int tr = threadIdx.x >> 6, tc = threadIdx.x & 63;
#pragma unroll
  for (int i = 0; i < 16; ++i) {
    int r = tr + i * 4;
    tile[r][tc] = W[(size_t)(k0 + r) * N + n0 + tc];
  }
  __syncthreads();
#pragma unroll
  for (int i = 0; i < 16; ++i) {
    int r = tr + i * 4;  // n offset
    Wt[(size_t)(n0 + r) * K + k0 + tc] = f2bf(tile[tc][r]);
  }
}

// ---------------- 128x128 bf16 MFMA GEMM tile (A[M][K], Bt[N][K]) ----------------
__device__ __forceinline__ void gemm_tile_128(
    const u16* __restrict__ A, const u16* __restrict__ Bt,
    const float* __restrict__ bias, float* __restrict__ C,
    int m0, int n0, int K, int ldc) {
  __shared__ __align__(16) u16 sA[128 * 32];
  __shared__ __align__(16) u16 sB[128 * 32];
  const int tid = threadIdx.x;
  const int lane = tid & 63;
  const int wave = tid >> 6;
  const int quad = lane >> 4;
  const int l15 = lane & 15;
  const int wm = (wave >> 1) << 6;
  const int wn = (wave & 1) << 6;

  f32x4 acc[4][4];
#pragma unroll
  for (int i = 0; i < 4; ++i)
#pragma unroll
    for (int j = 0; j < 4; ++j)
      acc[i][j] = (f32x4){0.f, 0.f, 0.f, 0.f};

  for (int kk = 0; kk < K; kk += 32) {
    __syncthreads();
#pragma unroll
    for (int it = 0; it < 2; ++it) {
      int c = tid + (it << 8);     // 512 chunks of 16B per tile
      int row = c >> 2;
      int ko = (c & 3) << 3;
      gll16((char*)sA + c * 16, A + (size_t)(m0 + row) * K + kk + ko);
      gll16((char*)sB + c * 16, Bt + (size_t)(n0 + row) * K + kk + ko);
    }
    __syncthreads();
    bf16x8 af[4], bfr[4];
#pragma unroll
    for (int i = 0; i < 4; ++i)
      af[i] = *(const bf16x8*)&sA[(wm + (i << 4) + l15) * 32 + quad * 8];
#pragma unroll
    for (int j = 0; j < 4; ++j)
      bfr[j] = *(const bf16x8*)&sB[(wn + (j << 4) + l15) * 32 + quad * 8];
#pragma unroll
    for (int i = 0; i < 4; ++i)
#pragma unroll
      for (int j = 0; j < 4; ++j)
        acc[i][j] = __builtin_amdgcn_mfma_f32_16x16x32_bf16(af[i], bfr[j], acc[i][j], 0, 0, 0);
  }

#pragma unroll
  for (int i = 0; i < 4; ++i) {
    int row = m0 + wm + (i << 4) + quad * 4;
#pragma unroll
    for (int j = 0; j < 4; ++j) {
      int col = n0 + wn + (j << 4) + l15;
      float bv = bias[col];
      float* cp = C + (size_t)row * ldc + col;
#pragma unroll
      for (int r = 0; r < 4; ++r)
        cp[(size_t)r * ldc] = acc[i][j][r] + bv;
    }
  }
}

__global__ __launch_bounds__(256) void k_gemm_qkv(
    const u16* __restrict__ X, const u16* __restrict__ Wqt,
    const u16* __restrict__ Wkt, const u16* __restrict__ Wvt,
    const float* __restrict__ bq, const float* __restrict__ bk,
    const float* __restrict__ bv, float* __restrict__ Qf,
    float* __restrict__ Kf, float* __restrict__ Vf) {
  int m0 = blockIdx.x << 7;
  int by = blockIdx.y;
  const u16* Bt; const float* bias; float* C; int n0, ldc;
  if (by < 16)      { Bt = Wqt; bias = bq; C = Qf; n0 = by << 7;        ldc = 2048; }
  else if (by < 20) { Bt = Wkt; bias = bk; C = Kf; n0 = (by - 16) << 7; ldc = 512;  }
  else              { Bt = Wvt; bias = bv; C = Vf; n0 = (by - 20) << 7; ldc = 512;  }
  gemm_tile_128(X, Bt, bias, C, m0, n0, 2048, ldc);
}

__global__ __launch_bounds__(256) void k_gemm_o(
    const u16* __restrict__ A, const u16* __restrict__ Wot,
    const float* __restrict__ bo, float* __restrict__ C) {
  gemm_tile_128(A, Wot, bo, C, blockIdx.x << 7, blockIdx.y << 7, 2048, 2048);
}

// ---------------- RoPE: Qf/Kf fp32 -> Qbf [b,h,s,d], Kbf [b,kvh,s,d] bf16 + past_key fp32 ----------------
__global__ __launch_bounds__(256) void k_rope(
    const float* __restrict__ Qf, const float* __restrict__ Kf,
    u16* __restrict__ Qbf, u16* __restrict__ Kbf, float* __restrict__ outK) {
  const int bx = blockIdx.x;         // b*S + s
  const int b = bx >> 11;
  const int s = bx & 2047;
  const int tid = threadIdx.x;
  // 1/sqrt(128) * log2(e) folded into Q so softmax can use exp2
  const float qscale = 0.08838834764831845f * 1.4426950408889634f;
  const float c1 = -13.287712379549449f / 64.f; // -log2(10000)/64

#pragma unroll
  for (int it = 0; it < 4; ++it) {
    int p = tid + (it << 8);
    int hh = p >> 6;
    int ii = p & 63;
    float ang = (float)s * exp2f((float)ii * c1);
    float cs, sn;
    sincosf(ang, &sn, &cs);
    const float* src = Qf + (size_t)bx * 2048 + hh * 128 + ii;
    float x1 = src[0], x2 = src[64];
    float o1 = (x1 * cs - x2 * sn) * qscale;
    float o2 = (x1 * sn + x2 * cs) * qscale;
    u16* dst = Qbf + ((size_t)(b * N_HEADS + hh) * S_LEN + s) * HEAD_D + ii;
    dst[0] = f2bf(o1);
    dst[64] = f2bf(o2);
  }
  {
    int hh = tid >> 6;   // kv head (4 heads * 64 pairs = 256 threads)
    int ii = tid & 63;
    float ang = (float)s * exp2f((float)ii * c1);
    float cs, sn;
    sincosf(ang, &sn, &cs);
    const float* src = Kf + (size_t)bx * 512 + hh * 128 + ii;
    float x1 = src[0], x2 = src[64];
    float o1 = x1 * cs - x2 * sn;
    float o2 = x1 * sn + x2 * cs;
    size_t idx = ((size_t)(b * N_KV + hh) * S_LEN + s) * HEAD_D + ii;
    Kbf[idx] = f2bf(o1);
    Kbf[idx + 64] = f2bf(o2);
    outK[idx] = o1;
    outK[idx + 64] = o2;
  }
}

// ---------------- V: Vf fp32 [b,s,kvh*d] -> Vt bf16 [b,kvh,d,s] + past_value fp32 ----------------
__global__ __launch_bounds__(256) void k_vtrans(const float* __restrict__ Vf,
                                                u16* __restrict__ Vt,
                                                float* __restrict__ outV) {
  __shared__ float tile[64][65];
  int s0 = blockIdx.x * 64, d0 = blockIdx.y * 64;
  int z = blockIdx.z;                 // b*N_KV + kvh
  int b = z >> 2, kvh = z & 3;
  int tr = threadIdx.x >> 6, tc = threadIdx.x & 63;
#pragma unroll
  for (int i = 0; i < 16; ++i) {
    int r = tr + i * 4;   // s offset
    float v = Vf[(size_t)(b * S_LEN + s0 + r) * 512 + kvh * 128 + d0 + tc];
    tile[r][tc] = v;
    outV[((size_t)z * S_LEN + s0 + r) * HEAD_D + d0 + tc] = v;
  }
  __syncthreads();
#pragma unroll
  for (int i = 0; i < 16; ++i) {
    int r = tr + i * 4;   // d offset
    Vt[((size_t)z * HEAD_D + d0 + r) * S_LEN + s0 + tc] = f2bf(tile[tc][r]);
  }
}

// ---------------- flash attention, S^T formulation, split-KV ----------------
// 128-row Q tile, 256 threads (4 waves x 32 q-rows) — r5's proven shape.
// Load balance fix: q-tiles 8..15 (18..32 KV tiles) are SPLIT into two blocks:
// chunk0 = tiles [0,16) (no diagonal), chunk1 = tiles [16, 2qt+2). Chunked
// blocks write unnormalized bf16 partial O + per-row (m,l); k_attn_combine
// merges. Block costs now 2..16 tiles (was 2..32), grid 768 (2/CU + 256
// backfill) -> no solo-rate tail.
// by decode (heavy-first): by<8: qt=8+by,c0 partial; by>=8: qt=23-by
//   (qt>=8 -> c1 partial; qt<8 -> full, final write).
__global__ __launch_bounds__(256, 2) void k_attn(
    const u16* __restrict__ Qbf, const u16* __restrict__ Kbf,
    const u16* __restrict__ Vt, u16* __restrict__ attn,
    u16* __restrict__ pO, float* __restrict__ pML) {
  __shared__ __align__(16) u16 smem[17920];   // 35840 B
  u16* sK = smem;            // 64 x 136  (8704)
  u16* sV = smem + 8704;     // 128 x 72  (9216)

  const int tid = threadIdx.x;
  const int lane = tid & 63;
  const int wave = tid >> 6;
  const int quad = lane >> 4;
  const int l15 = lane & 15;

  const int by = blockIdx.y;
  int qt, t0, t1, slot;
  bool finalw;
  if (by < 8) {               // heavy chunk0: 16 tiles, below-diagonal only
    qt = 8 + by; t0 = 0; t1 = 16; finalw = false;
    slot = ((blockIdx.x << 3) + (qt - 8)) << 1;
  } else {
    qt = 23 - by;
    if (qt >= 8) {            // heavy chunk1: diagonal part
      t0 = 16; t1 = 2 * qt + 2; finalw = false;
      slot = (((blockIdx.x << 3) + (qt - 8)) << 1) + 1;
    } else {                  // light q-tile: whole row, direct final write
      t0 = 0; t1 = 2 * qt + 2; finalw = true; slot = 0;
    }
  }

  const int bh = blockIdx.x;
  const int b = bh >> 4;
  const int h = bh & 15;
  const int kvh = h >> 2;
  const int q0 = qt << 7;
  const int qw = q0 + wave * 32;      // this wave's first q row

  const u16* Qb = Qbf + ((size_t)(b * N_HEADS + h) * S_LEN + qw) * HEAD_D;
  const u16* Kb = Kbf + (size_t)(b * N_KV + kvh) * S_LEN * HEAD_D;
  const u16* Vb = Vt + (size_t)(b * N_KV + kvh) * HEAD_D * S_LEN;

  // Q fragments (B-operand: lane holds Q[q=l15][d=quad*8+j]) for 2 row-groups
  bf16x8 aq[2][4];
#pragma unroll
  for (int i = 0; i < 2; ++i)
#pragma unroll
    for (int kc = 0; kc < 4; ++kc)
      aq[i][kc] = *(const bf16x8*)(Qb + (size_t)(i * 16 + l15) * HEAD_D + kc * 32 + quad * 8);

  float mst[2] = {-1e30f, -1e30f}, lst[2] = {0.f, 0.f};
  f32x4 oacc[2][8];
#pragma unroll
  for (int i = 0; i < 2; ++i)
#pragma unroll
    for (int n = 0; n < 8; ++n) oacc[i][n] = (f32x4){0.f, 0.f, 0.f, 0.f};

  for (int t = t0; t < t1; ++t) {
    const int kt0 = t << 6;
    __syncthreads();
    // stage K (64x17 chunks = 1088) + V (128x9 = 1152)
#pragma unroll
    for (int it = 0; it < 9; ++it) {
      int c = tid + (it << 8);
      if (c < 1088) {
        int row = c / 17;
        int k16 = c - row * 17;
        gll16((char*)sK + c * 16, Kb + (size_t)(kt0 + row) * HEAD_D + k16 * 8);
      } else if (c < 2240) {
        int vv = c - 1088;
        int d = vv / 9;
        int s16 = vv - d * 9;
        gll16((char*)sV + vv * 16, Vb + (size_t)d * S_LEN + kt0 + s16 * 8);
      }
    }
    __syncthreads();

    if (kt0 > qw + 31) continue;      // fully-masked for this wave (uniform branch)

    // S^T = K * Q^T : lane holds S[q=l15][s=quad*4+r] per 16x16 j-tile
    f32x4 st[2][4];
#pragma unroll
    for (int i = 0; i < 2; ++i)
#pragma unroll
      for (int j = 0; j < 4; ++j) st[i][j] = (f32x4){0.f, 0.f, 0.f, 0.f};
#pragma unroll
    for (int kc = 0; kc < 4; ++kc) {
#pragma unroll
      for (int j = 0; j < 4; ++j) {
        bf16x8 kf = *(const bf16x8*)&sK[(j * 16 + l15) * 136 + kc * 32 + quad * 8];
#pragma unroll
        for (int i = 0; i < 2; ++i)
          st[i][j] = __builtin_amdgcn_mfma_f32_16x16x32_bf16(kf, aq[i][kc], st[i][j], 0, 0, 0);
      }
    }

    if (kt0 + 63 > qw) {              // diagonal region: causal mask
#pragma unroll
      for (int i = 0; i < 2; ++i) {
        int q = qw + i * 16 + l15;
#pragma unroll
        for (int j = 0; j < 4; ++j) {
          int s = kt0 + j * 16 + quad * 4;
#pragma unroll
          for (int r = 0; r < 4; ++r)
            if (s + r > q) st[i][j][r] = -1e9f;
        }
      }
    }

    // online softmax; row stats live per-lane (q=l15), replicated across quads
    bf16x4 pf[2][4];
    float al[2];
#pragma unroll
    for (int i = 0; i < 2; ++i) {
      float m = -1e30f;
#pragma unroll
      for (int j = 0; j < 4; ++j)
#pragma unroll
        for (int r = 0; r < 4; ++r) m = fmaxf(m, st[i][j][r]);
      m = fmaxf(m, __shfl_xor(m, 16, 64));
      m = fmaxf(m, __shfl_xor(m, 32, 64));
      float mn = fmaxf(mst[i], m);
      al[i] = exp2f(mst[i] - mn);
      mst[i] = mn;
      float rs = 0.f;
#pragma unroll
      for (int j = 0; j < 4; ++j) {
        float p0 = exp2f(st[i][j][0] - mn);
        float p1 = exp2f(st[i][j][1] - mn);
        float p2 = exp2f(st[i][j][2] - mn);
        float p3 = exp2f(st[i][j][3] - mn);
        rs += (p0 + p1) + (p2 + p3);
        // pack 4 fp32 -> 4 bf16 via v_perm (half-up rounding)
        union { unsigned u[2]; bf16x4 v; } pk;
        pk.u[0] = __builtin_amdgcn_perm(__float_as_uint(p1) + 0x8000u,
                                        __float_as_uint(p0) + 0x8000u, 0x07060302u);
        pk.u[1] = __builtin_amdgcn_perm(__float_as_uint(p3) + 0x8000u,
                                        __float_as_uint(p2) + 0x8000u, 0x07060302u);
        pf[i][j] = pk.v;
      }
      rs += __shfl_xor(rs, 16, 64);
      rs += __shfl_xor(rs, 32, 64);
      lst[i] = lst[i] * al[i] + rs;
      // rescale O: rows of oacc are q=quad*4+r, fetch al for that row
#pragma unroll
      for (int r = 0; r < 4; ++r) {
        float a = __shfl(al[i], quad * 4 + r, 16);
#pragma unroll
        for (int n = 0; n < 8; ++n) oacc[i][n][r] *= a;
      }
    }

    // O += P*V via K=16 MFMA; P is already in A-layout in registers
#pragma unroll
    for (int j = 0; j < 4; ++j) {
#pragma unroll
      for (int n = 0; n < 8; ++n) {
        bf16x4 vf = *(const bf16x4*)&sV[(n * 16 + l15) * 72 + j * 16 + quad * 4];
#pragma unroll
        for (int i = 0; i < 2; ++i)
          oacc[i][n] = MFMA_PV(pf[i][j], vf, oacc[i][n]);
      }
    }
  }

  if (finalw) {
    // normalize + write [b, s, h, d] bf16 for the O-projection
#pragma unroll
    for (int i = 0; i < 2; ++i)
#pragma unroll
      for (int r = 0; r < 4; ++r) {
        float inv = 1.0f / __shfl(lst[i], quad * 4 + r, 16);
        int row = qw + i * 16 + quad * 4 + r;
        u16* op = attn + ((size_t)b * S_LEN + row) * HDIM + h * HEAD_D;
#pragma unroll
        for (int n = 0; n < 8; ++n)
          op[n * 16 + l15] = f2bf(oacc[i][n][r] * inv);
      }
  } else {
    // unnormalized partial O (bf16) + per-row m,l
    u16* po = pO + (size_t)slot * 16384;
#pragma unroll
    for (int i = 0; i < 2; ++i)
#pragma unroll
      for (int r = 0; r < 4; ++r) {
        int row = wave * 32 + i * 16 + quad * 4 + r;
#pragma unroll
        for (int n = 0; n < 8; ++n)
          po[row * 128 + n * 16 + l15] = f2bf(oacc[i][n][r]);
      }
    if (quad == 0) {
      float* ml = pML + slot * 256;
#pragma unroll
      for (int i = 0; i < 2; ++i) {
        int row = wave * 32 + i * 16 + l15;
        ml[row] = mst[i];
        ml[128 + row] = lst[i];
      }
    }
  }
}

// ---------------- combine the two partials of each heavy q-tile ----------------
__global__ __launch_bounds__(256) void k_attn_combine(
    const u16* __restrict__ pO, const float* __restrict__ pML,
    u16* __restrict__ attn) {
  const int bh = blockIdx.x;          // b*16 + h
  const int qt = 8 + blockIdx.y;
  const int b = bh >> 4;
  const int h = bh & 15;
  const int s0 = ((bh << 3) + blockIdx.y) << 1;   // slot pair base
  const int row = threadIdx.x >> 1;               // 0..127
  const int half = threadIdx.x & 1;               // 0..1 (64 cols each)

  const float* ml0 = pML + s0 * 256;
  const float* ml1 = pML + (s0 + 1) * 256;
  float m0 = ml0[row], l0 = ml0[128 + row];
  float m1 = ml1[row], l1 = ml1[128 + row];
  float m = fmaxf(m0, m1);
  float w0 = exp2f(m0 - m), w1 = exp2f(m1 - m);
  float inv = 1.0f / (l0 * w0 + l1 * w1);
  w0 *= inv; w1 *= inv;

  const u16* o0 = pO + (size_t)s0 * 16384 + row * 128 + half * 64;
  const u16* o1 = o0 + 16384;
  u16* op = attn + ((size_t)(b * S_LEN + (qt << 7) + row)) * HDIM + h * HEAD_D + half * 64;
#pragma unroll
  for (int k = 0; k < 8; ++k) {
    ushort4 a0 = ((const ushort4*)o0)[k * 2];
    ushort4 b0 = ((const ushort4*)o0)[k * 2 + 1];
    ushort4 a1 = ((const ushort4*)o1)[k * 2];
    ushort4 b1 = ((const ushort4*)o1)[k * 2 + 1];
    ushort4 ra, rb;
    ra.x = f2bf(bf2f(a0.x) * w0 + bf2f(a1.x) * w1);
    ra.y = f2bf(bf2f(a0.y) * w0 + bf2f(a1.y) * w1);
    ra.z = f2bf(bf2f(a0.z) * w0 + bf2f(a1.z) * w1);
    ra.w = f2bf(bf2f(a0.w) * w0 + bf2f(a1.w) * w1);
    rb.x = f2bf(bf2f(b0.x) * w0 + bf2f(b1.x) * w1);
    rb.y = f2bf(bf2f(b0.y) * w0 + bf2f(b1.y) * w1);
    rb.z = f2bf(bf2f(b0.z) * w0 + bf2f(b1.z) * w1);
    rb.w = f2bf(bf2f(b0.w) * w0 + bf2f(b1.w) * w1);
    ((ushort4*)op)[k * 2] = ra;
    ((ushort4*)op)[k * 2 + 1] = rb;
  }
}

// ---------------- launch ----------------
extern "C" void kernel_launch(void* const* d_in, const int* in_sizes, int n_in,
                              void* d_out, int out_size, void* d_ws, size_t ws_size,
                              hipStream_t stream) {
  (void)in_sizes; (void)n_in; (void)out_size; (void)ws_size;
  const float* hs = (const float*)d_in[0];
  // d_in[1] = mask (causality is computed analytically)
  const float* Wq = (const float*)d_in[2];
  const float* bq = (const float*)d_in[3];
  const float* Wk = (const float*)d_in[4];
  const float* bk = (const float*)d_in[5];
  const float* Wv = (const float*)d_in[6];
  const float* bv = (const float*)d_in[7];
  const float* Wo = (const float*)d_in[8];
  const float* bo = (const float*)d_in[9];
  float* out = (float*)d_out;

  char* ws = (char*)d_ws;
  u16* Xbf   = (u16*)(ws + 0);          // 16.8 MB
  u16* Wqt   = (u16*)(ws + 16777216);   // 8.4 MB
  u16* Wkt   = (u16*)(ws + 25165824);   // 2.1 MB
  u16* Wvt   = (u16*)(ws + 27262976);   // 2.1 MB
  u16* Wot   = (u16*)(ws + 29360128);   // 8.4 MB
  float* Qf  = (float*)(ws + 37748736); // 33.6 MB
  float* Kf  = (float*)(ws + 71303168); // 8.4 MB
  float* Vf  = (float*)(ws + 79691776); // 8.4 MB
  u16* Qbf   = (u16*)(ws + 88080384);   // 16.8 MB
  u16* Kbf   = (u16*)(ws + 104857600);  // 4.2 MB
  u16* Vtb   = (u16*)(ws + 109051904);  // 4.2 MB (+16B pad slack follows)
  u16* attnb = (u16*)(ws + 37748736);   // aliases Qf[0:16.8MB] (dead after k_rope)
  float* pML = (float*)(ws + 54525952); // aliases Qf[16.8:17.3MB] (512 slots x 256 f32)
  u16* pO    = (u16*)(ws + 71303168);   // aliases Kf+Vf (dead after rope/vtrans): 512 x 32KB

  k_convert<<<8192, 256, 0, stream>>>(hs, Xbf, 2097152);
  k_transpose_w<<<dim3(32, 32), 256, 0, stream>>>(Wq, Wqt, 2048, 2048);
  k_transpose_w<<<dim3(32, 8), 256, 0, stream>>>(Wk, Wkt, 2048, 512);
  k_transpose_w<<<dim3(32, 8), 256, 0, stream>>>(Wv, Wvt, 2048, 512);
  k_transpose_w<<<dim3(32, 32), 256, 0, stream>>>(Wo, Wot, 2048, 2048);
  k_gemm_qkv<<<dim3(32, 24), 256, 0, stream>>>(Xbf, Wqt, Wkt, Wvt, bq, bk, bv, Qf, Kf, Vf);
  k_rope<<<4096, 256, 0, stream>>>(Qf, Kf, Qbf, Kbf, out + 8388608);
  k_vtrans<<<dim3(32, 2, 8), 256, 0, stream>>>(Vf, Vtb, out + 10485760);
  k_attn<<<dim3(32, 24), 256, 0, stream>>>(Qbf, Kbf, Vtb, attnb, pO, pML);
  k_attn_combine<<<dim3(32, 8), 256, 0, stream>>>(pO, pML, attnb);
  k_gemm_o<<<dim3(32, 16), 256, 0, stream>>>(attnb, Wot, bo, out);
}